// Round 6
// baseline (1937.190 us; speedup 1.0000x reference)
//
#include <hip/hip_runtime.h>
#include <math.h>

#define N_NODES 100000
#define N_EDGES 500000
#define N_PATHS 3
#define DIM 128
#define K_LAYERS 10
#define NBLK_PER_PATH ((N_NODES + 255) / 256)   // 391

// ---------------- degree histogram, all paths ----------------
__global__ __launch_bounds__(256) void deg_kernel(const int* __restrict__ edges,
                                                  int* __restrict__ degS,
                                                  int* __restrict__ degD) {
    int idx = blockIdx.x * 256 + threadIdx.x;
    if (idx < N_PATHS * N_EDGES) {
        int p = idx / N_EDGES;
        int e = idx - p * N_EDGES;
        const int* src = edges + (size_t)p * 2 * N_EDGES;
        const int* dst = src + N_EDGES;
        atomicAdd(&degS[p * N_NODES + src[e]], 1);
        atomicAdd(&degD[p * N_NODES + dst[e]], 1);
    }
}

// ---------------- normalization factors, all paths ----------------
__global__ __launch_bounds__(256) void norm_kernel(const int* __restrict__ degS,
                                                   const int* __restrict__ degD,
                                                   float* __restrict__ norm_s,
                                                   float* __restrict__ norm_d) {
    int n = blockIdx.x * 256 + threadIdx.x;
    if (n < N_PATHS * N_NODES) {
        norm_s[n] = 1.0f / sqrtf(fmaxf((float)degS[n], 1.0f));
        norm_d[n] = 1.0f / sqrtf(fmaxf((float)degD[n], 1.0f));
    }
}

// ---------------- hierarchical scan: phase A - per-block sums ----------------
__global__ __launch_bounds__(256) void blocksum_kernel(const int* __restrict__ cnt,
                                                       int* __restrict__ bsum) {
    int b = blockIdx.x;
    int p = b / NBLK_PER_PATH;
    int lb = b - p * NBLK_PER_PATH;
    int idx = lb * 256 + threadIdx.x;
    int v = (idx < N_NODES) ? cnt[p * N_NODES + idx] : 0;
#pragma unroll
    for (int off = 32; off; off >>= 1) v += __shfl_xor(v, off);
    __shared__ int ws[4];
    if ((threadIdx.x & 63) == 0) ws[threadIdx.x >> 6] = v;
    __syncthreads();
    if (threadIdx.x == 0) bsum[b] = ws[0] + ws[1] + ws[2] + ws[3];
}

// ---------------- phase B - scan the 391 block sums per path (3 blocks) --------
__global__ __launch_bounds__(512) void bscan_kernel(int* __restrict__ bsum) {
    __shared__ int s[512];
    int p = blockIdx.x;
    int t = threadIdx.x;
    int v = (t < NBLK_PER_PATH) ? bsum[p * NBLK_PER_PATH + t] : 0;
    s[t] = v;
    __syncthreads();
    for (int off = 1; off < 512; off <<= 1) {
        int x = s[t];
        int a = (t >= off) ? s[t - off] : 0;
        __syncthreads();
        s[t] = x + a;
        __syncthreads();
    }
    if (t < NBLK_PER_PATH) bsum[p * NBLK_PER_PATH + t] = s[t] - v;   // exclusive
}

// ---------------- phase C - block-local rescan + write row_ptr/cursor ----------
__global__ __launch_bounds__(256) void scan_write_kernel(const int* __restrict__ cnt,
                                                         const int* __restrict__ bsum,
                                                         int* __restrict__ row_ptr_all,
                                                         int* __restrict__ cursor_all) {
    __shared__ int s[256];
    int b = blockIdx.x;
    int p = b / NBLK_PER_PATH;
    int lb = b - p * NBLK_PER_PATH;
    int idx = lb * 256 + threadIdx.x;
    int t = threadIdx.x;
    int v = (idx < N_NODES) ? cnt[p * N_NODES + idx] : 0;
    s[t] = v;
    __syncthreads();
    for (int off = 1; off < 256; off <<= 1) {
        int x = s[t];
        int a = (t >= off) ? s[t - off] : 0;
        __syncthreads();
        s[t] = x + a;
        __syncthreads();
    }
    int excl = s[t] - v + bsum[b];
    if (idx < N_NODES) {
        row_ptr_all[p * (N_NODES + 1) + idx] = excl;
        cursor_all[p * N_NODES + idx] = excl;
        if (idx == N_NODES - 1)
            row_ptr_all[p * (N_NODES + 1) + N_NODES] = excl + v;
    }
}

// ---------------- fill CSR: col=src, weight=0.9*norm_s[src]*norm_d[dst] ----------------
__global__ __launch_bounds__(256) void fill_kernel(const int* __restrict__ edges,
                                                   const float* __restrict__ norm_s,
                                                   const float* __restrict__ norm_d,
                                                   int* __restrict__ cursor,
                                                   int2* __restrict__ cw) {
    int idx = blockIdx.x * 256 + threadIdx.x;
    if (idx < N_PATHS * N_EDGES) {
        int p = idx / N_EDGES;
        int e = idx - p * N_EDGES;
        const int* src = edges + (size_t)p * 2 * N_EDGES;
        const int* dst = src + N_EDGES;
        int s = src[e], d = dst[e];
        int pos = atomicAdd(&cursor[p * N_NODES + d], 1);
        float w = 0.9f * norm_s[p * N_NODES + s] * norm_d[p * N_NODES + d];
        cw[(size_t)p * N_EDGES + pos] = make_int2(s, __float_as_int(w));
    }
}

// ---------------- f32 -> bf16 cast of h (once) ----------------
__global__ __launch_bounds__(256) void cast_kernel(const float4* __restrict__ in,
                                                   ushort4* __restrict__ outp) {
    int idx = blockIdx.x * 256 + threadIdx.x;
    if (idx < N_NODES * DIM / 4) {
        float4 v = in[idx];
        ushort4 o;
        unsigned u;
        u = __float_as_uint(v.x); o.x = (unsigned short)((u + 0x7fff + ((u >> 16) & 1)) >> 16);
        u = __float_as_uint(v.y); o.y = (unsigned short)((u + 0x7fff + ((u >> 16) & 1)) >> 16);
        u = __float_as_uint(v.z); o.z = (unsigned short)((u + 0x7fff + ((u >> 16) & 1)) >> 16);
        u = __float_as_uint(v.w); o.w = (unsigned short)((u + 0x7fff + ((u >> 16) & 1)) >> 16);
        outp[idx] = o;
    }
}

__device__ __forceinline__ unsigned bf16pack(float a, float b) {
    unsigned ua = __float_as_uint(a), ub = __float_as_uint(b);
    ua = (ua + 0x7fffu + ((ua >> 16) & 1)) >> 16;
    ub = (ub + 0x7fffu + ((ub >> 16) & 1)) >> 16;
    return ua | (ub << 16);
}

// ---------------- one APPNP layer, bf16 state, 3 paths fused -------------------
// One wave per node (node wave-uniform -> edge records via scalar loads).
// bf16 row = 256B; half-wave (32 lanes x 8B) gathers one row; 2 edges per step,
// per-half edge selected from SGPRs by cndmask. f32 accumulate, f32 h-term.
// OUT_F32=1 for the final layer (writes f32 z).
template <int OUT_F32>
__global__ __launch_bounds__(256) void prop_kernel(const unsigned short* __restrict__ xin,
                                                   size_t in_stride,   // elems per path (0 = shared)
                                                   const float* __restrict__ h0,
                                                   void* __restrict__ xout,
                                                   const int* __restrict__ row_ptr,
                                                   const int2* __restrict__ cw) {
    int node_g = blockIdx.x * 4 + (threadIdx.x >> 6);   // 0 .. 3*N_NODES-1
    int lane = threadIdx.x & 63;
    int half = lane >> 5;
    int ql   = lane & 31;
    int p = node_g / N_NODES;
    int node = node_g - p * N_NODES;
    const int* rp = row_ptr + p * (N_NODES + 1);
    const int2* cwp = cw + (size_t)p * N_EDGES;
    const uint2* xin2 = (const uint2*)(xin + (size_t)p * in_stride);  // 32 uint2 per row

    int beg = rp[node];
    int end = rp[node + 1];
    float a0 = 0.f, a1 = 0.f, a2 = 0.f, a3 = 0.f;

#define ACC4(v, w)                                              \
    {                                                           \
        a0 = fmaf(w, __uint_as_float((v).x << 16), a0);         \
        a1 = fmaf(w, __uint_as_float((v).x & 0xffff0000u), a1); \
        a2 = fmaf(w, __uint_as_float((v).y << 16), a2);         \
        a3 = fmaf(w, __uint_as_float((v).y & 0xffff0000u), a3); \
    }

    int i = beg;
    for (; i + 8 <= end; i += 8) {       // 8 edges = 4 gather instrs in flight
        int2 e0 = cwp[i + 0], e1 = cwp[i + 1], e2 = cwp[i + 2], e3 = cwp[i + 3];
        int2 e4 = cwp[i + 4], e5 = cwp[i + 5], e6 = cwp[i + 6], e7 = cwp[i + 7];
        int   c0 = half ? e1.x : e0.x;  float w0 = __int_as_float(half ? e1.y : e0.y);
        int   c1 = half ? e3.x : e2.x;  float w1 = __int_as_float(half ? e3.y : e2.y);
        int   c2 = half ? e5.x : e4.x;  float w2 = __int_as_float(half ? e5.y : e4.y);
        int   c3 = half ? e7.x : e6.x;  float w3 = __int_as_float(half ? e7.y : e6.y);
        uint2 v0 = xin2[(size_t)c0 * 32 + ql];
        uint2 v1 = xin2[(size_t)c1 * 32 + ql];
        uint2 v2 = xin2[(size_t)c2 * 32 + ql];
        uint2 v3 = xin2[(size_t)c3 * 32 + ql];
        ACC4(v0, w0); ACC4(v1, w1); ACC4(v2, w2); ACC4(v3, w3);
    }
    for (; i < end; i += 2) {            // tail pairs (odd tail: upper half w=0)
        int2 e0 = cwp[i];
        bool hasB = (i + 1 < end);
        int2 e1 = hasB ? cwp[i + 1] : e0;
        int   c = half ? e1.x : e0.x;
        float w = __int_as_float(half ? e1.y : e0.y);
        if (half && !hasB) w = 0.f;
        uint2 v = xin2[(size_t)c * 32 + ql];
        ACC4(v, w);
    }
#undef ACC4

    // combine the two half-wave edge subsets (same columns)
    a0 += __shfl_xor(a0, 32);
    a1 += __shfl_xor(a1, 32);
    a2 += __shfl_xor(a2, 32);
    a3 += __shfl_xor(a3, 32);

    if (half == 0) {
        float4 hv = ((const float4*)(h0 + (size_t)node * DIM))[ql];
        a0 += 0.1f * hv.x;
        a1 += 0.1f * hv.y;
        a2 += 0.1f * hv.z;
        a3 += 0.1f * hv.w;
        if (OUT_F32) {
            float* zo = (float*)xout + (size_t)p * N_NODES * DIM;
            ((float4*)zo)[(size_t)node * 32 + ql] = make_float4(a0, a1, a2, a3);
        } else {
            unsigned short* xo = (unsigned short*)xout + (size_t)p * N_NODES * DIM;
            ((uint2*)xo)[(size_t)node * 32 + ql] = make_uint2(bf16pack(a0, a1), bf16pack(a2, a3));
        }
    }
}

__device__ __forceinline__ float fast_tanh(float x) {
    float e = __expf(2.0f * x);
    return 1.0f - 2.0f / (e + 1.0f);   // == (e-1)/(e+1) == tanh(x)
}

// ---------------- attention logits: wsum[p] += sum_n tanh(z_row@W1+b1)@w2 ----------------
__global__ __launch_bounds__(256) void attn_kernel(const float* __restrict__ z,
                                                   const float* __restrict__ W1,
                                                   const float* __restrict__ b1,
                                                   const float* __restrict__ w2,
                                                   float* __restrict__ wsum) {
    __shared__ float W1s[DIM * DIM];        // 64 KB
    __shared__ float zt[4][8 * DIM];        // 16 KB, one 8-row tile per wave
    for (int i = threadIdx.x; i < DIM * DIM; i += 256) W1s[i] = W1[i];
    __syncthreads();

    const int wid  = threadIdx.x >> 6;      // 0..3
    const int lane = threadIdx.x & 63;
    const int c4 = (lane & 31) * 4;
    const int rh = lane >> 5;
    float* myz = zt[wid];

    float4 bias = *(const float4*)(b1 + c4);
    float4 wv   = *(const float4*)(w2 + c4);

    float accP0 = 0.f, accP1 = 0.f, accP2 = 0.f;
    const int NTILES = N_PATHS * N_NODES / 8;
    const int TPP = N_NODES / 8;
    const int tstride = gridDim.x * 4;

    int t = blockIdx.x * 4 + wid;
    float4 pre0, pre1, pre2, pre3;
    if (t < NTILES) {
        const float4* g = (const float4*)(z + (size_t)t * 8 * DIM);
        pre0 = g[lane]; pre1 = g[64 + lane]; pre2 = g[128 + lane]; pre3 = g[192 + lane];
    }
    for (; t < NTILES; t += tstride) {
        *(float4*)&myz[lane * 4]              = pre0;
        *(float4*)&myz[(64 + lane) * 4]       = pre1;
        *(float4*)&myz[(128 + lane) * 4]      = pre2;
        *(float4*)&myz[(192 + lane) * 4]      = pre3;
        asm volatile("s_waitcnt lgkmcnt(0)" ::: "memory");
        int tn = t + tstride;
        if (tn < NTILES) {
            const float4* g = (const float4*)(z + (size_t)tn * 8 * DIM);
            pre0 = g[lane]; pre1 = g[64 + lane]; pre2 = g[128 + lane]; pre3 = g[192 + lane];
        }
        float acc[4][4];
#pragma unroll
        for (int r = 0; r < 4; ++r)
#pragma unroll
            for (int j = 0; j < 4; ++j) acc[r][j] = 0.f;

        for (int k = 0; k < DIM; k += 4) {
            float4 w0 = *(const float4*)&W1s[(k + 0) * DIM + c4];
            float4 w1_ = *(const float4*)&W1s[(k + 1) * DIM + c4];
            float4 w2_ = *(const float4*)&W1s[(k + 2) * DIM + c4];
            float4 w3_ = *(const float4*)&W1s[(k + 3) * DIM + c4];
#pragma unroll
            for (int r = 0; r < 4; ++r) {
                float4 zv = *(const float4*)&myz[(rh * 4 + r) * DIM + k];
                acc[r][0] = fmaf(zv.x, w0.x, acc[r][0]);
                acc[r][1] = fmaf(zv.x, w0.y, acc[r][1]);
                acc[r][2] = fmaf(zv.x, w0.z, acc[r][2]);
                acc[r][3] = fmaf(zv.x, w0.w, acc[r][3]);
                acc[r][0] = fmaf(zv.y, w1_.x, acc[r][0]);
                acc[r][1] = fmaf(zv.y, w1_.y, acc[r][1]);
                acc[r][2] = fmaf(zv.y, w1_.z, acc[r][2]);
                acc[r][3] = fmaf(zv.y, w1_.w, acc[r][3]);
                acc[r][0] = fmaf(zv.z, w2_.x, acc[r][0]);
                acc[r][1] = fmaf(zv.z, w2_.y, acc[r][1]);
                acc[r][2] = fmaf(zv.z, w2_.z, acc[r][2]);
                acc[r][3] = fmaf(zv.z, w2_.w, acc[r][3]);
                acc[r][0] = fmaf(zv.w, w3_.x, acc[r][0]);
                acc[r][1] = fmaf(zv.w, w3_.y, acc[r][1]);
                acc[r][2] = fmaf(zv.w, w3_.z, acc[r][2]);
                acc[r][3] = fmaf(zv.w, w3_.w, acc[r][3]);
            }
        }
        float psum = 0.f;
#pragma unroll
        for (int r = 0; r < 4; ++r) {
            psum += fast_tanh(acc[r][0] + bias.x) * wv.x;
            psum += fast_tanh(acc[r][1] + bias.y) * wv.y;
            psum += fast_tanh(acc[r][2] + bias.z) * wv.z;
            psum += fast_tanh(acc[r][3] + bias.w) * wv.w;
        }
#pragma unroll
        for (int off = 32; off; off >>= 1) psum += __shfl_xor(psum, off);
        if (lane == 0) {
            int p = t / TPP;
            if (p == 0) accP0 += psum;
            else if (p == 1) accP1 += psum;
            else accP2 += psum;
        }
    }
    if (lane == 0) {
        if (accP0 != 0.f) atomicAdd(&wsum[0], accP0);
        if (accP1 != 0.f) atomicAdd(&wsum[1], accP1);
        if (accP2 != 0.f) atomicAdd(&wsum[2], accP2);
    }
}

// ---------------- beta = softmax(wsum / N) over 3 paths ----------------
__global__ void beta_kernel(const float* __restrict__ wsum, float* __restrict__ beta) {
    if (threadIdx.x == 0 && blockIdx.x == 0) {
        float w0 = wsum[0] * (1.0f / N_NODES);
        float w1 = wsum[1] * (1.0f / N_NODES);
        float w2v = wsum[2] * (1.0f / N_NODES);
        float m = fmaxf(w0, fmaxf(w1, w2v));
        float e0 = expf(w0 - m), e1 = expf(w1 - m), e2 = expf(w2v - m);
        float inv = 1.0f / (e0 + e1 + e2);
        beta[0] = e0 * inv;
        beta[1] = e1 * inv;
        beta[2] = e2 * inv;
    }
}

// ---------------- out[n,:] = sum_p beta[p] * z[p,n,:] ----------------
__global__ __launch_bounds__(256) void combine_kernel(const float4* __restrict__ z4,
                                                      const float* __restrict__ beta,
                                                      float4* __restrict__ out4) {
    size_t idx = (size_t)blockIdx.x * 256 + threadIdx.x;
    const size_t M = (size_t)N_NODES * 32;
    if (idx < M) {
        float b0 = beta[0], b1 = beta[1], b2 = beta[2];
        float4 a = z4[idx];
        float4 b = z4[M + idx];
        float4 c = z4[2 * M + idx];
        float4 o;
        o.x = b0 * a.x + b1 * b.x + b2 * c.x;
        o.y = b0 * a.y + b1 * b.y + b2 * c.y;
        o.z = b0 * a.z + b1 * b.z + b2 * c.z;
        o.w = b0 * a.w + b1 * b.w + b2 * c.w;
        out4[idx] = o;
    }
}

extern "C" void kernel_launch(void* const* d_in, const int* in_sizes, int n_in,
                              void* d_out, int out_size, void* d_ws, size_t ws_size,
                              hipStream_t stream) {
    const float* h     = (const float*)d_in[0];
    const int*   edges = (const int*)d_in[1];   // (3, 2, 500000) int32
    const float* W1    = (const float*)d_in[2];
    const float* b1    = (const float*)d_in[3];
    const float* w2    = (const float*)d_in[4];
    float* out = (float*)d_out;

    // ---- workspace carve ----
    // z is written only by the final prop layer; buf1 and hb alias its space
    // (both dead before layer 9 writes z).
    char* ws = (char*)d_ws;
    float* z = (float*)ws;               ws += (size_t)N_PATHS * N_NODES * DIM * 4;  // 153.6 MB
    unsigned short* buf0 = (unsigned short*)ws; ws += (size_t)N_PATHS * N_NODES * DIM * 2;  // 76.8 MB
    int2* cw = (int2*)ws;                ws += (size_t)N_PATHS * N_EDGES * 8;        // 12 MB
    int* row_ptr = (int*)ws;             ws += (size_t)N_PATHS * (N_NODES + 1) * 4 + 12;
    int* cursor = (int*)ws;              ws += (size_t)N_PATHS * N_NODES * 4;
    float* norm_s = (float*)ws;          ws += (size_t)N_PATHS * N_NODES * 4;
    float* norm_d = (float*)ws;          ws += (size_t)N_PATHS * N_NODES * 4;
    int* degS = (int*)ws;                ws += (size_t)N_PATHS * N_NODES * 4;
    int* degD = (int*)ws;                ws += (size_t)N_PATHS * N_NODES * 4;  // adjacent to degS
    int* bsum = (int*)ws;                ws += (size_t)N_PATHS * NBLK_PER_PATH * 4;
    float* wsum = (float*)ws;            ws += 4 * 4;
    float* beta = (float*)ws;            ws += 4 * 4;
    // aliases inside z:
    unsigned short* buf1 = (unsigned short*)z;                                   // 76.8 MB
    unsigned short* hb   = (unsigned short*)z + (size_t)N_PATHS * N_NODES * DIM; // 25.6 MB

    const size_t PSTRIDE = (size_t)N_NODES * DIM;   // per-path elems

    // ---- CSR build, all 3 paths batched ----
    hipMemsetAsync(degS, 0, (size_t)2 * N_PATHS * N_NODES * 4, stream);
    deg_kernel<<<(N_PATHS * N_EDGES + 255) / 256, 256, 0, stream>>>(edges, degS, degD);
    norm_kernel<<<(N_PATHS * N_NODES + 255) / 256, 256, 0, stream>>>(degS, degD, norm_s, norm_d);
    blocksum_kernel<<<N_PATHS * NBLK_PER_PATH, 256, 0, stream>>>(degD, bsum);
    bscan_kernel<<<N_PATHS, 512, 0, stream>>>(bsum);
    scan_write_kernel<<<N_PATHS * NBLK_PER_PATH, 256, 0, stream>>>(degD, bsum, row_ptr, cursor);
    fill_kernel<<<(N_PATHS * N_EDGES + 255) / 256, 256, 0, stream>>>(edges, norm_s, norm_d, cursor, cw);

    // ---- bf16 copy of h (gather source for layer 0) ----
    cast_kernel<<<(N_NODES * DIM / 4 + 255) / 256, 256, 0, stream>>>(
        (const float4*)h, (ushort4*)hb);

    // ---- APPNP propagation: 10 fused layers over all 3 paths ----
    const int pgrid = N_PATHS * N_NODES / 4;   // 75000 blocks, 1 wave per node
    // layer 0: hb (shared, stride 0) -> buf0
    prop_kernel<0><<<pgrid, 256, 0, stream>>>(hb, 0, h, buf0, row_ptr, cw);
    // layers 1..8 alternate buf0 <-> buf1
    for (int i = 1; i <= 8; ++i) {
        const unsigned short* src_b = (i & 1) ? buf0 : buf1;
        unsigned short* dst_b       = (i & 1) ? buf1 : buf0;
        prop_kernel<0><<<pgrid, 256, 0, stream>>>(src_b, PSTRIDE, h, dst_b, row_ptr, cw);
    }
    // layer 9: buf0 -> z (f32); buf1/hb (aliased in z) are dead now
    prop_kernel<1><<<pgrid, 256, 0, stream>>>(buf0, PSTRIDE, h, z, row_ptr, cw);

    // ---- semantic attention ----
    hipMemsetAsync(wsum, 0, 3 * 4, stream);
    attn_kernel<<<1024, 256, 0, stream>>>(z, W1, b1, w2, wsum);
    beta_kernel<<<1, 64, 0, stream>>>(wsum, beta);
    combine_kernel<<<(N_NODES * 32 + 255) / 256, 256, 0, stream>>>(
        (const float4*)z, beta, (float4*)out);
}

// Round 7
// 1195.838 us; speedup vs baseline: 1.6199x; 1.6199x over previous
//
#include <hip/hip_runtime.h>
#include <math.h>

#define N_NODES 100000
#define N_EDGES 500000
#define N_PATHS 3
#define DIM 128
#define K_LAYERS 10
#define NBLK_PER_PATH ((N_NODES + 255) / 256)   // 391

typedef __attribute__((ext_vector_type(8))) short bf16x8;
typedef __attribute__((ext_vector_type(4))) float f32x4;

// ---------------- degree histogram, all paths ----------------
__global__ __launch_bounds__(256) void deg_kernel(const int* __restrict__ edges,
                                                  int* __restrict__ degS,
                                                  int* __restrict__ degD) {
    int idx = blockIdx.x * 256 + threadIdx.x;
    if (idx < N_PATHS * N_EDGES) {
        int p = idx / N_EDGES;
        int e = idx - p * N_EDGES;
        const int* src = edges + (size_t)p * 2 * N_EDGES;
        const int* dst = src + N_EDGES;
        atomicAdd(&degS[p * N_NODES + src[e]], 1);
        atomicAdd(&degD[p * N_NODES + dst[e]], 1);
    }
}

// ---------------- normalization factors, all paths ----------------
__global__ __launch_bounds__(256) void norm_kernel(const int* __restrict__ degS,
                                                   const int* __restrict__ degD,
                                                   float* __restrict__ norm_s,
                                                   float* __restrict__ norm_d) {
    int n = blockIdx.x * 256 + threadIdx.x;
    if (n < N_PATHS * N_NODES) {
        norm_s[n] = 1.0f / sqrtf(fmaxf((float)degS[n], 1.0f));
        norm_d[n] = 1.0f / sqrtf(fmaxf((float)degD[n], 1.0f));
    }
}

// ---------------- hierarchical scan: phase A - per-block sums ----------------
__global__ __launch_bounds__(256) void blocksum_kernel(const int* __restrict__ cnt,
                                                       int* __restrict__ bsum) {
    int b = blockIdx.x;
    int p = b / NBLK_PER_PATH;
    int lb = b - p * NBLK_PER_PATH;
    int idx = lb * 256 + threadIdx.x;
    int v = (idx < N_NODES) ? cnt[p * N_NODES + idx] : 0;
#pragma unroll
    for (int off = 32; off; off >>= 1) v += __shfl_xor(v, off);
    __shared__ int ws[4];
    if ((threadIdx.x & 63) == 0) ws[threadIdx.x >> 6] = v;
    __syncthreads();
    if (threadIdx.x == 0) bsum[b] = ws[0] + ws[1] + ws[2] + ws[3];
}

// ---------------- phase B - scan the 391 block sums per path (3 blocks) --------
__global__ __launch_bounds__(512) void bscan_kernel(int* __restrict__ bsum) {
    __shared__ int s[512];
    int p = blockIdx.x;
    int t = threadIdx.x;
    int v = (t < NBLK_PER_PATH) ? bsum[p * NBLK_PER_PATH + t] : 0;
    s[t] = v;
    __syncthreads();
    for (int off = 1; off < 512; off <<= 1) {
        int x = s[t];
        int a = (t >= off) ? s[t - off] : 0;
        __syncthreads();
        s[t] = x + a;
        __syncthreads();
    }
    if (t < NBLK_PER_PATH) bsum[p * NBLK_PER_PATH + t] = s[t] - v;   // exclusive
}

// ---------------- phase C - block-local rescan + write row_ptr/cursor ----------
__global__ __launch_bounds__(256) void scan_write_kernel(const int* __restrict__ cnt,
                                                         const int* __restrict__ bsum,
                                                         int* __restrict__ row_ptr_all,
                                                         int* __restrict__ cursor_all) {
    __shared__ int s[256];
    int b = blockIdx.x;
    int p = b / NBLK_PER_PATH;
    int lb = b - p * NBLK_PER_PATH;
    int idx = lb * 256 + threadIdx.x;
    int t = threadIdx.x;
    int v = (idx < N_NODES) ? cnt[p * N_NODES + idx] : 0;
    s[t] = v;
    __syncthreads();
    for (int off = 1; off < 256; off <<= 1) {
        int x = s[t];
        int a = (t >= off) ? s[t - off] : 0;
        __syncthreads();
        s[t] = x + a;
        __syncthreads();
    }
    int excl = s[t] - v + bsum[b];
    if (idx < N_NODES) {
        row_ptr_all[p * (N_NODES + 1) + idx] = excl;
        cursor_all[p * N_NODES + idx] = excl;
        if (idx == N_NODES - 1)
            row_ptr_all[p * (N_NODES + 1) + N_NODES] = excl + v;
    }
}

// ---------------- fill CSR: col=src, weight=0.9*norm_s[src]*norm_d[dst] ----------------
__global__ __launch_bounds__(256) void fill_kernel(const int* __restrict__ edges,
                                                   const float* __restrict__ norm_s,
                                                   const float* __restrict__ norm_d,
                                                   int* __restrict__ cursor,
                                                   int2* __restrict__ cw) {
    int idx = blockIdx.x * 256 + threadIdx.x;
    if (idx < N_PATHS * N_EDGES) {
        int p = idx / N_EDGES;
        int e = idx - p * N_EDGES;
        const int* src = edges + (size_t)p * 2 * N_EDGES;
        const int* dst = src + N_EDGES;
        int s = src[e], d = dst[e];
        int pos = atomicAdd(&cursor[p * N_NODES + d], 1);
        float w = 0.9f * norm_s[p * N_NODES + s] * norm_d[p * N_NODES + d];
        cw[(size_t)p * N_EDGES + pos] = make_int2(s, __float_as_int(w));
    }
}

__device__ __forceinline__ unsigned bf16pack(float a, float b) {
    unsigned ua = __float_as_uint(a), ub = __float_as_uint(b);
    ua = (ua + 0x7fffu + ((ua >> 16) & 1)) >> 16;
    ub = (ub + 0x7fffu + ((ub >> 16) & 1)) >> 16;
    return ua | (ub << 16);
}

// ---------------- f32 -> bf16 cast of h (once) ----------------
__global__ __launch_bounds__(256) void cast_kernel(const float4* __restrict__ in,
                                                   ushort4* __restrict__ outp) {
    int idx = blockIdx.x * 256 + threadIdx.x;
    if (idx < N_NODES * DIM / 4) {
        float4 v = in[idx];
        ushort4 o;
        unsigned u;
        u = __float_as_uint(v.x); o.x = (unsigned short)((u + 0x7fff + ((u >> 16) & 1)) >> 16);
        u = __float_as_uint(v.y); o.y = (unsigned short)((u + 0x7fff + ((u >> 16) & 1)) >> 16);
        u = __float_as_uint(v.z); o.z = (unsigned short)((u + 0x7fff + ((u >> 16) & 1)) >> 16);
        u = __float_as_uint(v.w); o.w = (unsigned short)((u + 0x7fff + ((u >> 16) & 1)) >> 16);
        outp[idx] = o;
    }
}

// ---------------- W1^T bf16 (128x128, once) ----------------
__global__ __launch_bounds__(256) void w1t_kernel(const float* __restrict__ W1,
                                                  unsigned short* __restrict__ W1t) {
    int idx = blockIdx.x * 256 + threadIdx.x;
    if (idx < DIM * DIM) {
        int c = idx >> 7, k = idx & 127;     // W1t[c][k] = bf16(W1[k][c])
        unsigned u = __float_as_uint(W1[k * DIM + c]);
        W1t[idx] = (unsigned short)((u + 0x7fff + ((u >> 16) & 1)) >> 16);
    }
}

// ---------------- one APPNP layer, bf16 state, quarter-wave: 4 nodes per wave ----
// bf16 row = 256B = 16 lanes x 16B -> one gather instruction per edge, with 4
// independent per-node latency chains per wave. f32 accumulate, f32 h anchor.
template <int OUT_F32>
__global__ __launch_bounds__(256) void prop_kernel(const unsigned short* __restrict__ xin,
                                                   size_t in_stride,    // elems per path (0 = shared)
                                                   const float* __restrict__ h0f,
                                                   void* __restrict__ xout,
                                                   const int* __restrict__ row_ptr,
                                                   const int2* __restrict__ cw) {
    int wid  = threadIdx.x >> 6;
    int lane = threadIdx.x & 63;
    int q    = lane >> 4;          // quarter 0..3 = node slot
    int ql   = lane & 15;          // uint4 column within row
    int nodeBase = blockIdx.x * 16 + wid * 4;    // wave-uniform; 100000%4==0 -> one path per wave
    int p  = nodeBase / N_NODES;
    int nb = nodeBase - p * N_NODES;
    const int*  rp   = row_ptr + p * (N_NODES + 1);
    const int2* cwp  = cw + (size_t)p * N_EDGES;
    const uint4* xin4 = (const uint4*)(xin + (size_t)p * in_stride);

    // row_ptr[nb..nb+4]: 5 lanes load, broadcast
    int rv = 0;
    if (lane < 5) rv = rp[nb + lane];
    int beg = __shfl(rv, q);
    int end = __shfl(rv, q + 1);
    int deg = end - beg;
    int myNode = nb + q;
    // wave-max degree (deg is quarter-uniform)
    int maxd = deg;
    maxd = max(maxd, __shfl_xor(maxd, 16));
    maxd = max(maxd, __shfl_xor(maxd, 32));

    float a0 = 0.f, a1 = 0.f, a2 = 0.f, a3 = 0.f;
    float a4 = 0.f, a5 = 0.f, a6 = 0.f, a7 = 0.f;

    for (int base = 0; base < maxd; base += 16) {
        int2 e = make_int2(0, 0);
        if (base + ql < deg) e = cwp[beg + base + ql];   // per-quarter coalesced preload
        int lim = maxd - base; if (lim > 16) lim = 16;
#pragma unroll 4
        for (int j = 0; j < lim; ++j) {
            int lsrc = (lane & 48) | j;
            int   c = __shfl(e.x, lsrc);
            float w = __int_as_float(__shfl(e.y, lsrc));
            if (base + j < deg) {      // quarter-uniform exec mask
                uint4 v = xin4[(size_t)c * 16 + ql];
                a0 = fmaf(w, __uint_as_float(v.x << 16), a0);
                a1 = fmaf(w, __uint_as_float(v.x & 0xffff0000u), a1);
                a2 = fmaf(w, __uint_as_float(v.y << 16), a2);
                a3 = fmaf(w, __uint_as_float(v.y & 0xffff0000u), a3);
                a4 = fmaf(w, __uint_as_float(v.z << 16), a4);
                a5 = fmaf(w, __uint_as_float(v.z & 0xffff0000u), a5);
                a6 = fmaf(w, __uint_as_float(v.w << 16), a6);
                a7 = fmaf(w, __uint_as_float(v.w & 0xffff0000u), a7);
            }
        }
    }

    // f32 anchor: lane ql owns elems 8ql..8ql+7 = float4 slots 2ql, 2ql+1
    const float4* h4 = (const float4*)(h0f + (size_t)myNode * DIM);
    float4 h0v = h4[ql * 2];
    float4 h1v = h4[ql * 2 + 1];
    a0 += 0.1f * h0v.x; a1 += 0.1f * h0v.y; a2 += 0.1f * h0v.z; a3 += 0.1f * h0v.w;
    a4 += 0.1f * h1v.x; a5 += 0.1f * h1v.y; a6 += 0.1f * h1v.z; a7 += 0.1f * h1v.w;

    size_t row = (size_t)p * N_NODES + myNode;
    if (OUT_F32) {
        float4* zo = (float4*)xout + row * 32;
        zo[ql * 2]     = make_float4(a0, a1, a2, a3);
        zo[ql * 2 + 1] = make_float4(a4, a5, a6, a7);
    } else {
        uint4 o;
        o.x = bf16pack(a0, a1);
        o.y = bf16pack(a2, a3);
        o.z = bf16pack(a4, a5);
        o.w = bf16pack(a6, a7);
        ((uint4*)xout)[row * 16 + ql] = o;
    }
}

__device__ __forceinline__ float fast_tanh(float x) {
    float e = __expf(2.0f * x);
    return 1.0f - 2.0f / (e + 1.0f);   // == (e-1)/(e+1) == tanh(x)
}

// ---------------- attention logits via MFMA: wsum[p] += sum_n tanh(z@W1+b1)@w2 ----
// One wave per 16-row z tile (grid-strided). B (W1^T bf16) fragments preloaded to
// registers (8 ntiles x 4 ksteps); A packed f32->bf16 on the fly from z.
// D layout (verified): col=lane&15, row=(lane>>4)*4+reg.
__global__ __launch_bounds__(256) void attn_kernel(const float* __restrict__ z,
                                                   const unsigned short* __restrict__ W1t,
                                                   const float* __restrict__ b1,
                                                   const float* __restrict__ w2,
                                                   float* __restrict__ wsum) {
    const int wid  = threadIdx.x >> 6;
    const int lane = threadIdx.x & 63;
    const int c0   = lane & 15;        // column within n-tile / row within a-tile
    const int kh   = lane >> 4;        // k-chunk selector (k = kh*8 + j)

    // preload all B fragments: Bf[nt][ks] = W1t[nt*16+c0][ks*32 + kh*8 ..+8]
    const bf16x8* w1t8 = (const bf16x8*)W1t;
    bf16x8 Bf[8][4];
#pragma unroll
    for (int nt = 0; nt < 8; ++nt)
#pragma unroll
        for (int ks = 0; ks < 4; ++ks)
            Bf[nt][ks] = w1t8[(nt * 16 + c0) * 16 + ks * 4 + kh];

    float b1v[8], w2v[8];
#pragma unroll
    for (int nt = 0; nt < 8; ++nt) {
        b1v[nt] = b1[nt * 16 + c0];
        w2v[nt] = w2[nt * 16 + c0];
    }

    float accP0 = 0.f, accP1 = 0.f, accP2 = 0.f;
    const int NTILES = N_PATHS * N_NODES / 16;   // 18750
    const int TPP    = N_NODES / 16;             // 6250
    const int stride = gridDim.x * 4;
    const float4* zf4 = (const float4*)z;

    for (int t = blockIdx.x * 4 + wid; t < NTILES; t += stride) {
        // A fragments: row = 16t + c0, k = ks*32 + kh*8 + j  (pack f32->bf16)
        size_t rbase = ((size_t)t * 16 + c0) * 32 + kh * 2;
        bf16x8 Af[4];
#pragma unroll
        for (int ks = 0; ks < 4; ++ks) {
            float4 x0 = zf4[rbase + ks * 8];
            float4 x1 = zf4[rbase + ks * 8 + 1];
            union { uint4 u; bf16x8 v; } cv;
            cv.u.x = bf16pack(x0.x, x0.y);
            cv.u.y = bf16pack(x0.z, x0.w);
            cv.u.z = bf16pack(x1.x, x1.y);
            cv.u.w = bf16pack(x1.z, x1.w);
            Af[ks] = cv.v;
        }
        f32x4 acc[8];
#pragma unroll
        for (int nt = 0; nt < 8; ++nt) acc[nt] = (f32x4){0.f, 0.f, 0.f, 0.f};
#pragma unroll
        for (int nt = 0; nt < 8; ++nt)
#pragma unroll
            for (int ks = 0; ks < 4; ++ks)
                acc[nt] = __builtin_amdgcn_mfma_f32_16x16x32_bf16(Af[ks], Bf[nt][ks], acc[nt], 0, 0, 0);

        float psum = 0.f;
#pragma unroll
        for (int nt = 0; nt < 8; ++nt) {
            psum += fast_tanh(acc[nt][0] + b1v[nt]) * w2v[nt];
            psum += fast_tanh(acc[nt][1] + b1v[nt]) * w2v[nt];
            psum += fast_tanh(acc[nt][2] + b1v[nt]) * w2v[nt];
            psum += fast_tanh(acc[nt][3] + b1v[nt]) * w2v[nt];
        }
#pragma unroll
        for (int off = 32; off; off >>= 1) psum += __shfl_xor(psum, off);
        if (lane == 0) {
            int p = t / TPP;
            if (p == 0) accP0 += psum;
            else if (p == 1) accP1 += psum;
            else accP2 += psum;
        }
    }
    if (lane == 0) {
        if (accP0 != 0.f) atomicAdd(&wsum[0], accP0);
        if (accP1 != 0.f) atomicAdd(&wsum[1], accP1);
        if (accP2 != 0.f) atomicAdd(&wsum[2], accP2);
    }
}

// ---------------- beta = softmax(wsum / N) over 3 paths ----------------
__global__ void beta_kernel(const float* __restrict__ wsum, float* __restrict__ beta) {
    if (threadIdx.x == 0 && blockIdx.x == 0) {
        float w0 = wsum[0] * (1.0f / N_NODES);
        float w1 = wsum[1] * (1.0f / N_NODES);
        float w2v = wsum[2] * (1.0f / N_NODES);
        float m = fmaxf(w0, fmaxf(w1, w2v));
        float e0 = expf(w0 - m), e1 = expf(w1 - m), e2 = expf(w2v - m);
        float inv = 1.0f / (e0 + e1 + e2);
        beta[0] = e0 * inv;
        beta[1] = e1 * inv;
        beta[2] = e2 * inv;
    }
}

// ---------------- out[n,:] = sum_p beta[p] * z[p,n,:] ----------------
__global__ __launch_bounds__(256) void combine_kernel(const float4* __restrict__ z4,
                                                      const float* __restrict__ beta,
                                                      float4* __restrict__ out4) {
    size_t idx = (size_t)blockIdx.x * 256 + threadIdx.x;
    const size_t M = (size_t)N_NODES * 32;
    if (idx < M) {
        float b0 = beta[0], b1 = beta[1], b2 = beta[2];
        float4 a = z4[idx];
        float4 b = z4[M + idx];
        float4 c = z4[2 * M + idx];
        float4 o;
        o.x = b0 * a.x + b1 * b.x + b2 * c.x;
        o.y = b0 * a.y + b1 * b.y + b2 * c.y;
        o.z = b0 * a.z + b1 * b.z + b2 * c.z;
        o.w = b0 * a.w + b1 * b.w + b2 * c.w;
        out4[idx] = o;
    }
}

extern "C" void kernel_launch(void* const* d_in, const int* in_sizes, int n_in,
                              void* d_out, int out_size, void* d_ws, size_t ws_size,
                              hipStream_t stream) {
    const float* h     = (const float*)d_in[0];
    const int*   edges = (const int*)d_in[1];   // (3, 2, 500000) int32
    const float* W1    = (const float*)d_in[2];
    const float* b1    = (const float*)d_in[3];
    const float* w2    = (const float*)d_in[4];
    float* out = (float*)d_out;

    // ---- workspace carve ----
    // z written only by the final prop layer; buf1 and hb alias its space.
    char* ws = (char*)d_ws;
    float* z = (float*)ws;               ws += (size_t)N_PATHS * N_NODES * DIM * 4;  // 153.6 MB
    unsigned short* buf0 = (unsigned short*)ws; ws += (size_t)N_PATHS * N_NODES * DIM * 2;  // 76.8 MB
    int2* cw = (int2*)ws;                ws += (size_t)N_PATHS * N_EDGES * 8;        // 12 MB
    int* row_ptr = (int*)ws;             ws += (size_t)N_PATHS * (N_NODES + 1) * 4 + 12;
    int* cursor = (int*)ws;              ws += (size_t)N_PATHS * N_NODES * 4;
    float* norm_s = (float*)ws;          ws += (size_t)N_PATHS * N_NODES * 4;
    float* norm_d = (float*)ws;          ws += (size_t)N_PATHS * N_NODES * 4;
    int* degS = (int*)ws;                ws += (size_t)N_PATHS * N_NODES * 4;
    int* degD = (int*)ws;                ws += (size_t)N_PATHS * N_NODES * 4;  // adjacent to degS
    int* bsum = (int*)ws;                ws += (size_t)N_PATHS * NBLK_PER_PATH * 4;
    float* wsum = (float*)ws;            ws += 4 * 4;
    float* beta = (float*)ws;            ws += 4 * 4;
    unsigned short* W1t = (unsigned short*)ws; ws += (size_t)DIM * DIM * 2;          // 32 KB
    // aliases inside z (dead before layer 9 writes z):
    unsigned short* buf1 = (unsigned short*)z;                                   // 76.8 MB
    unsigned short* hb   = (unsigned short*)z + (size_t)N_PATHS * N_NODES * DIM; // 25.6 MB

    const size_t PSTRIDE = (size_t)N_NODES * DIM;   // per-path elems

    // ---- CSR build, all 3 paths batched ----
    hipMemsetAsync(degS, 0, (size_t)2 * N_PATHS * N_NODES * 4, stream);
    deg_kernel<<<(N_PATHS * N_EDGES + 255) / 256, 256, 0, stream>>>(edges, degS, degD);
    norm_kernel<<<(N_PATHS * N_NODES + 255) / 256, 256, 0, stream>>>(degS, degD, norm_s, norm_d);
    blocksum_kernel<<<N_PATHS * NBLK_PER_PATH, 256, 0, stream>>>(degD, bsum);
    bscan_kernel<<<N_PATHS, 512, 0, stream>>>(bsum);
    scan_write_kernel<<<N_PATHS * NBLK_PER_PATH, 256, 0, stream>>>(degD, bsum, row_ptr, cursor);
    fill_kernel<<<(N_PATHS * N_EDGES + 255) / 256, 256, 0, stream>>>(edges, norm_s, norm_d, cursor, cw);

    // ---- one-time casts ----
    cast_kernel<<<(N_NODES * DIM / 4 + 255) / 256, 256, 0, stream>>>(
        (const float4*)h, (ushort4*)hb);
    w1t_kernel<<<(DIM * DIM + 255) / 256, 256, 0, stream>>>(W1, W1t);

    // ---- APPNP propagation: 10 fused layers over all 3 paths ----
    const int pgrid = N_PATHS * N_NODES / 16;   // 18750 blocks, 4 nodes/wave
    prop_kernel<0><<<pgrid, 256, 0, stream>>>(hb, 0, h, buf0, row_ptr, cw);
    for (int i = 1; i <= 8; ++i) {
        const unsigned short* src_b = (i & 1) ? buf0 : buf1;
        unsigned short* dst_b       = (i & 1) ? buf1 : buf0;
        prop_kernel<0><<<pgrid, 256, 0, stream>>>(src_b, PSTRIDE, h, dst_b, row_ptr, cw);
    }
    prop_kernel<1><<<pgrid, 256, 0, stream>>>(buf0, PSTRIDE, h, z, row_ptr, cw);

    // ---- semantic attention (MFMA) ----
    hipMemsetAsync(wsum, 0, 3 * 4, stream);
    attn_kernel<<<512, 256, 0, stream>>>(z, W1t, b1, w2, wsum);
    beta_kernel<<<1, 64, 0, stream>>>(wsum, beta);
    combine_kernel<<<(N_NODES * 32 + 255) / 256, 256, 0, stream>>>(
        (const float4*)z, beta, (float4*)out);
}

// Round 8
// 1191.823 us; speedup vs baseline: 1.6254x; 1.0034x over previous
//
#include <hip/hip_runtime.h>
#include <math.h>

#define N_NODES 100000
#define N_EDGES 500000
#define N_PATHS 3
#define DIM 128
#define K_LAYERS 10
#define NBLK_PER_PATH ((N_NODES + 255) / 256)   // 391
#define PN (N_PATHS * N_NODES)                  // 300000
#define NSHARD 8

typedef __attribute__((ext_vector_type(8))) short bf16x8;
typedef __attribute__((ext_vector_type(4))) float f32x4;

// ---------------- degree histogram, XCD-sharded ----------------
// shard = blockIdx&7 tracks the default round-robin wg->XCD mapping, so each
// shard's counter lines stay in ONE XCD's L2 (no cross-XCD atomic ping-pong).
__global__ __launch_bounds__(256) void deg_kernel(const int* __restrict__ edges,
                                                  int* __restrict__ degS8,
                                                  int* __restrict__ degD8) {
    int idx = blockIdx.x * 256 + threadIdx.x;
    int shard = blockIdx.x & (NSHARD - 1);
    if (idx < N_PATHS * N_EDGES) {
        int p = idx / N_EDGES;
        int e = idx - p * N_EDGES;
        const int* src = edges + (size_t)p * 2 * N_EDGES;
        const int* dst = src + N_EDGES;
        atomicAdd(&degS8[shard * PN + p * N_NODES + src[e]], 1);
        atomicAdd(&degD8[shard * PN + p * N_NODES + dst[e]], 1);
    }
}

// ---------------- reduce shards -> norms + total in-degree ----------------
__global__ __launch_bounds__(256) void norm_reduce_kernel(const int* __restrict__ degS8,
                                                          const int* __restrict__ degD8,
                                                          float* __restrict__ norm_s,
                                                          float* __restrict__ norm_d,
                                                          int* __restrict__ degD_tot) {
    int i = blockIdx.x * 256 + threadIdx.x;
    if (i < PN) {
        int sS = 0, sD = 0;
#pragma unroll
        for (int s = 0; s < NSHARD; ++s) {
            sS += degS8[s * PN + i];
            sD += degD8[s * PN + i];
        }
        norm_s[i] = 1.0f / sqrtf(fmaxf((float)sS, 1.0f));
        norm_d[i] = 1.0f / sqrtf(fmaxf((float)sD, 1.0f));
        degD_tot[i] = sD;
    }
}

// ---------------- hierarchical scan: phase A - per-block sums ----------------
__global__ __launch_bounds__(256) void blocksum_kernel(const int* __restrict__ cnt,
                                                       int* __restrict__ bsum) {
    int b = blockIdx.x;
    int p = b / NBLK_PER_PATH;
    int lb = b - p * NBLK_PER_PATH;
    int idx = lb * 256 + threadIdx.x;
    int v = (idx < N_NODES) ? cnt[p * N_NODES + idx] : 0;
#pragma unroll
    for (int off = 32; off; off >>= 1) v += __shfl_xor(v, off);
    __shared__ int ws[4];
    if ((threadIdx.x & 63) == 0) ws[threadIdx.x >> 6] = v;
    __syncthreads();
    if (threadIdx.x == 0) bsum[b] = ws[0] + ws[1] + ws[2] + ws[3];
}

// ---------------- phase B - scan the 391 block sums per path (3 blocks) --------
__global__ __launch_bounds__(512) void bscan_kernel(int* __restrict__ bsum) {
    __shared__ int s[512];
    int p = blockIdx.x;
    int t = threadIdx.x;
    int v = (t < NBLK_PER_PATH) ? bsum[p * NBLK_PER_PATH + t] : 0;
    s[t] = v;
    __syncthreads();
    for (int off = 1; off < 512; off <<= 1) {
        int x = s[t];
        int a = (t >= off) ? s[t - off] : 0;
        __syncthreads();
        s[t] = x + a;
        __syncthreads();
    }
    if (t < NBLK_PER_PATH) bsum[p * NBLK_PER_PATH + t] = s[t] - v;   // exclusive
}

// ---------------- phase C - block-local rescan + write row_ptr ----------------
__global__ __launch_bounds__(256) void scan_write_kernel(const int* __restrict__ cnt,
                                                         const int* __restrict__ bsum,
                                                         int* __restrict__ row_ptr_all) {
    __shared__ int s[256];
    int b = blockIdx.x;
    int p = b / NBLK_PER_PATH;
    int lb = b - p * NBLK_PER_PATH;
    int idx = lb * 256 + threadIdx.x;
    int t = threadIdx.x;
    int v = (idx < N_NODES) ? cnt[p * N_NODES + idx] : 0;
    s[t] = v;
    __syncthreads();
    for (int off = 1; off < 256; off <<= 1) {
        int x = s[t];
        int a = (t >= off) ? s[t - off] : 0;
        __syncthreads();
        s[t] = x + a;
        __syncthreads();
    }
    int excl = s[t] - v + bsum[b];
    if (idx < N_NODES) {
        row_ptr_all[p * (N_NODES + 1) + idx] = excl;
        if (idx == N_NODES - 1)
            row_ptr_all[p * (N_NODES + 1) + N_NODES] = excl + v;
    }
}

// ---------------- per-shard cursors: shard s owns a sub-range of each row ------
__global__ __launch_bounds__(256) void cursor_init_kernel(const int* __restrict__ row_ptr_all,
                                                          const int* __restrict__ degD8,
                                                          int* __restrict__ cursor8) {
    int i = blockIdx.x * 256 + threadIdx.x;
    if (i < PN) {
        int p = i / N_NODES;
        int n = i - p * N_NODES;
        int c = row_ptr_all[p * (N_NODES + 1) + n];
#pragma unroll
        for (int s = 0; s < NSHARD; ++s) {
            cursor8[s * PN + i] = c;
            c += degD8[s * PN + i];
        }
    }
}

// ---------------- fill CSR: col=src, weight=0.9*norm_s[src]*norm_d[dst] --------
// cursor atomics go to this block's shard -> local-L2, no ping-pong.
__global__ __launch_bounds__(256) void fill_kernel(const int* __restrict__ edges,
                                                   const float* __restrict__ norm_s,
                                                   const float* __restrict__ norm_d,
                                                   int* __restrict__ cursor8,
                                                   int2* __restrict__ cw) {
    int idx = blockIdx.x * 256 + threadIdx.x;
    int shard = blockIdx.x & (NSHARD - 1);
    if (idx < N_PATHS * N_EDGES) {
        int p = idx / N_EDGES;
        int e = idx - p * N_EDGES;
        const int* src = edges + (size_t)p * 2 * N_EDGES;
        const int* dst = src + N_EDGES;
        int s = src[e], d = dst[e];
        int pos = atomicAdd(&cursor8[shard * PN + p * N_NODES + d], 1);
        float w = 0.9f * norm_s[p * N_NODES + s] * norm_d[p * N_NODES + d];
        cw[(size_t)p * N_EDGES + pos] = make_int2(s, __float_as_int(w));
    }
}

__device__ __forceinline__ unsigned bf16pack(float a, float b) {
    unsigned ua = __float_as_uint(a), ub = __float_as_uint(b);
    ua = (ua + 0x7fffu + ((ua >> 16) & 1)) >> 16;
    ub = (ub + 0x7fffu + ((ub >> 16) & 1)) >> 16;
    return ua | (ub << 16);
}

// ---------------- f32 -> bf16 cast of h (once) ----------------
__global__ __launch_bounds__(256) void cast_kernel(const float4* __restrict__ in,
                                                   ushort4* __restrict__ outp) {
    int idx = blockIdx.x * 256 + threadIdx.x;
    if (idx < N_NODES * DIM / 4) {
        float4 v = in[idx];
        ushort4 o;
        unsigned u;
        u = __float_as_uint(v.x); o.x = (unsigned short)((u + 0x7fff + ((u >> 16) & 1)) >> 16);
        u = __float_as_uint(v.y); o.y = (unsigned short)((u + 0x7fff + ((u >> 16) & 1)) >> 16);
        u = __float_as_uint(v.z); o.z = (unsigned short)((u + 0x7fff + ((u >> 16) & 1)) >> 16);
        u = __float_as_uint(v.w); o.w = (unsigned short)((u + 0x7fff + ((u >> 16) & 1)) >> 16);
        outp[idx] = o;
    }
}

// ---------------- W1^T bf16 (128x128, once) ----------------
__global__ __launch_bounds__(256) void w1t_kernel(const float* __restrict__ W1,
                                                  unsigned short* __restrict__ W1t) {
    int idx = blockIdx.x * 256 + threadIdx.x;
    if (idx < DIM * DIM) {
        int c = idx >> 7, k = idx & 127;     // W1t[c][k] = bf16(W1[k][c])
        unsigned u = __float_as_uint(W1[k * DIM + c]);
        W1t[idx] = (unsigned short)((u + 0x7fff + ((u >> 16) & 1)) >> 16);
    }
}

// ---------------- one APPNP layer, bf16 state, quarter-wave: 4 nodes per wave ----
template <int OUT_F32>
__global__ __launch_bounds__(256) void prop_kernel(const unsigned short* __restrict__ xin,
                                                   size_t in_stride,    // elems per path (0 = shared)
                                                   const float* __restrict__ h0f,
                                                   void* __restrict__ xout,
                                                   const int* __restrict__ row_ptr,
                                                   const int2* __restrict__ cw) {
    int wid  = threadIdx.x >> 6;
    int lane = threadIdx.x & 63;
    int q    = lane >> 4;          // quarter 0..3 = node slot
    int ql   = lane & 15;          // uint4 column within row
    int nodeBase = blockIdx.x * 16 + wid * 4;    // wave-uniform; one path per wave
    int p  = nodeBase / N_NODES;
    int nb = nodeBase - p * N_NODES;
    const int*  rp   = row_ptr + p * (N_NODES + 1);
    const int2* cwp  = cw + (size_t)p * N_EDGES;
    const uint4* xin4 = (const uint4*)(xin + (size_t)p * in_stride);

    int rv = 0;
    if (lane < 5) rv = rp[nb + lane];
    int beg = __shfl(rv, q);
    int end = __shfl(rv, q + 1);
    int deg = end - beg;
    int myNode = nb + q;
    int maxd = deg;
    maxd = max(maxd, __shfl_xor(maxd, 16));
    maxd = max(maxd, __shfl_xor(maxd, 32));

    float a0 = 0.f, a1 = 0.f, a2 = 0.f, a3 = 0.f;
    float a4 = 0.f, a5 = 0.f, a6 = 0.f, a7 = 0.f;

    for (int base = 0; base < maxd; base += 16) {
        int2 e = make_int2(0, 0);
        if (base + ql < deg) e = cwp[beg + base + ql];   // per-quarter coalesced preload
        int lim = maxd - base; if (lim > 16) lim = 16;
#pragma unroll 4
        for (int j = 0; j < lim; ++j) {
            int lsrc = (lane & 48) | j;
            int   c = __shfl(e.x, lsrc);
            float w = __int_as_float(__shfl(e.y, lsrc));
            if (base + j < deg) {      // quarter-uniform exec mask
                uint4 v = xin4[(size_t)c * 16 + ql];
                a0 = fmaf(w, __uint_as_float(v.x << 16), a0);
                a1 = fmaf(w, __uint_as_float(v.x & 0xffff0000u), a1);
                a2 = fmaf(w, __uint_as_float(v.y << 16), a2);
                a3 = fmaf(w, __uint_as_float(v.y & 0xffff0000u), a3);
                a4 = fmaf(w, __uint_as_float(v.z << 16), a4);
                a5 = fmaf(w, __uint_as_float(v.z & 0xffff0000u), a5);
                a6 = fmaf(w, __uint_as_float(v.w << 16), a6);
                a7 = fmaf(w, __uint_as_float(v.w & 0xffff0000u), a7);
            }
        }
    }

    const float4* h4 = (const float4*)(h0f + (size_t)myNode * DIM);
    float4 h0v = h4[ql * 2];
    float4 h1v = h4[ql * 2 + 1];
    a0 += 0.1f * h0v.x; a1 += 0.1f * h0v.y; a2 += 0.1f * h0v.z; a3 += 0.1f * h0v.w;
    a4 += 0.1f * h1v.x; a5 += 0.1f * h1v.y; a6 += 0.1f * h1v.z; a7 += 0.1f * h1v.w;

    size_t row = (size_t)p * N_NODES + myNode;
    if (OUT_F32) {
        float4* zo = (float4*)xout + row * 32;
        zo[ql * 2]     = make_float4(a0, a1, a2, a3);
        zo[ql * 2 + 1] = make_float4(a4, a5, a6, a7);
    } else {
        uint4 o;
        o.x = bf16pack(a0, a1);
        o.y = bf16pack(a2, a3);
        o.z = bf16pack(a4, a5);
        o.w = bf16pack(a6, a7);
        ((uint4*)xout)[row * 16 + ql] = o;
    }
}

__device__ __forceinline__ float fast_tanh(float x) {
    float e = __expf(2.0f * x);
    return 1.0f - 2.0f / (e + 1.0f);   // == (e-1)/(e+1) == tanh(x)
}

// ---------------- attention logits via MFMA ----------------
__global__ __launch_bounds__(256) void attn_kernel(const float* __restrict__ z,
                                                   const unsigned short* __restrict__ W1t,
                                                   const float* __restrict__ b1,
                                                   const float* __restrict__ w2,
                                                   float* __restrict__ wsum) {
    const int wid  = threadIdx.x >> 6;
    const int lane = threadIdx.x & 63;
    const int c0   = lane & 15;
    const int kh   = lane >> 4;

    const bf16x8* w1t8 = (const bf16x8*)W1t;
    bf16x8 Bf[8][4];
#pragma unroll
    for (int nt = 0; nt < 8; ++nt)
#pragma unroll
        for (int ks = 0; ks < 4; ++ks)
            Bf[nt][ks] = w1t8[(nt * 16 + c0) * 16 + ks * 4 + kh];

    float b1v[8], w2v[8];
#pragma unroll
    for (int nt = 0; nt < 8; ++nt) {
        b1v[nt] = b1[nt * 16 + c0];
        w2v[nt] = w2[nt * 16 + c0];
    }

    float accP0 = 0.f, accP1 = 0.f, accP2 = 0.f;
    const int NTILES = N_PATHS * N_NODES / 16;   // 18750
    const int TPP    = N_NODES / 16;             // 6250
    const int stride = gridDim.x * 4;
    const float4* zf4 = (const float4*)z;

    for (int t = blockIdx.x * 4 + wid; t < NTILES; t += stride) {
        size_t rbase = ((size_t)t * 16 + c0) * 32 + kh * 2;
        bf16x8 Af[4];
#pragma unroll
        for (int ks = 0; ks < 4; ++ks) {
            float4 x0 = zf4[rbase + ks * 8];
            float4 x1 = zf4[rbase + ks * 8 + 1];
            union { uint4 u; bf16x8 v; } cv;
            cv.u.x = bf16pack(x0.x, x0.y);
            cv.u.y = bf16pack(x0.z, x0.w);
            cv.u.z = bf16pack(x1.x, x1.y);
            cv.u.w = bf16pack(x1.z, x1.w);
            Af[ks] = cv.v;
        }
        f32x4 acc[8];
#pragma unroll
        for (int nt = 0; nt < 8; ++nt) acc[nt] = (f32x4){0.f, 0.f, 0.f, 0.f};
#pragma unroll
        for (int nt = 0; nt < 8; ++nt)
#pragma unroll
            for (int ks = 0; ks < 4; ++ks)
                acc[nt] = __builtin_amdgcn_mfma_f32_16x16x32_bf16(Af[ks], Bf[nt][ks], acc[nt], 0, 0, 0);

        float psum = 0.f;
#pragma unroll
        for (int nt = 0; nt < 8; ++nt) {
            psum += fast_tanh(acc[nt][0] + b1v[nt]) * w2v[nt];
            psum += fast_tanh(acc[nt][1] + b1v[nt]) * w2v[nt];
            psum += fast_tanh(acc[nt][2] + b1v[nt]) * w2v[nt];
            psum += fast_tanh(acc[nt][3] + b1v[nt]) * w2v[nt];
        }
#pragma unroll
        for (int off = 32; off; off >>= 1) psum += __shfl_xor(psum, off);
        if (lane == 0) {
            int p = t / TPP;
            if (p == 0) accP0 += psum;
            else if (p == 1) accP1 += psum;
            else accP2 += psum;
        }
    }
    if (lane == 0) {
        if (accP0 != 0.f) atomicAdd(&wsum[0], accP0);
        if (accP1 != 0.f) atomicAdd(&wsum[1], accP1);
        if (accP2 != 0.f) atomicAdd(&wsum[2], accP2);
    }
}

// ---------------- beta = softmax(wsum / N) over 3 paths ----------------
__global__ void beta_kernel(const float* __restrict__ wsum, float* __restrict__ beta) {
    if (threadIdx.x == 0 && blockIdx.x == 0) {
        float w0 = wsum[0] * (1.0f / N_NODES);
        float w1 = wsum[1] * (1.0f / N_NODES);
        float w2v = wsum[2] * (1.0f / N_NODES);
        float m = fmaxf(w0, fmaxf(w1, w2v));
        float e0 = expf(w0 - m), e1 = expf(w1 - m), e2 = expf(w2v - m);
        float inv = 1.0f / (e0 + e1 + e2);
        beta[0] = e0 * inv;
        beta[1] = e1 * inv;
        beta[2] = e2 * inv;
    }
}

// ---------------- out[n,:] = sum_p beta[p] * z[p,n,:] ----------------
__global__ __launch_bounds__(256) void combine_kernel(const float4* __restrict__ z4,
                                                      const float* __restrict__ beta,
                                                      float4* __restrict__ out4) {
    size_t idx = (size_t)blockIdx.x * 256 + threadIdx.x;
    const size_t M = (size_t)N_NODES * 32;
    if (idx < M) {
        float b0 = beta[0], b1 = beta[1], b2 = beta[2];
        float4 a = z4[idx];
        float4 b = z4[M + idx];
        float4 c = z4[2 * M + idx];
        float4 o;
        o.x = b0 * a.x + b1 * b.x + b2 * c.x;
        o.y = b0 * a.y + b1 * b.y + b2 * c.y;
        o.z = b0 * a.z + b1 * b.z + b2 * c.z;
        o.w = b0 * a.w + b1 * b.w + b2 * c.w;
        out4[idx] = o;
    }
}

extern "C" void kernel_launch(void* const* d_in, const int* in_sizes, int n_in,
                              void* d_out, int out_size, void* d_ws, size_t ws_size,
                              hipStream_t stream) {
    const float* h     = (const float*)d_in[0];
    const int*   edges = (const int*)d_in[1];   // (3, 2, 500000) int32
    const float* W1    = (const float*)d_in[2];
    const float* b1    = (const float*)d_in[3];
    const float* w2    = (const float*)d_in[4];
    float* out = (float*)d_out;

    // ---- workspace carve ----
    char* ws = (char*)d_ws;
    float* z = (float*)ws;               ws += (size_t)N_PATHS * N_NODES * DIM * 4;  // 153.6 MB
    unsigned short* buf0 = (unsigned short*)ws; ws += (size_t)N_PATHS * N_NODES * DIM * 2;  // 76.8 MB
    int2* cw = (int2*)ws;                ws += (size_t)N_PATHS * N_EDGES * 8;        // 12 MB
    int* row_ptr = (int*)ws;             ws += (size_t)N_PATHS * (N_NODES + 1) * 4 + 12;
    float* norm_s = (float*)ws;          ws += (size_t)PN * 4;
    float* norm_d = (float*)ws;          ws += (size_t)PN * 4;
    int* bsum = (int*)ws;                ws += (size_t)N_PATHS * NBLK_PER_PATH * 4;
    float* wsum = (float*)ws;            ws += 4 * 4;
    float* beta = (float*)ws;            ws += 4 * 4;
    unsigned short* W1t = (unsigned short*)ws; ws += (size_t)DIM * DIM * 2;          // 32 KB
    // CSR-build temporaries live inside buf0 (dead until prop layer 0 writes it):
    int* degS8    = (int*)buf0;                       // 9.6 MB
    int* degD8    = degS8 + (size_t)NSHARD * PN;      // 9.6 MB
    int* cursor8  = degD8 + (size_t)NSHARD * PN;      // 9.6 MB
    int* degD_tot = cursor8 + (size_t)NSHARD * PN;    // 1.2 MB   (total 30 MB < 76.8)
    // aliases inside z (dead before layer 9 writes z):
    unsigned short* buf1 = (unsigned short*)z;                                   // 76.8 MB
    unsigned short* hb   = (unsigned short*)z + (size_t)N_PATHS * N_NODES * DIM; // 25.6 MB

    const size_t PSTRIDE = (size_t)N_NODES * DIM;   // per-path elems

    // ---- CSR build, all 3 paths batched, XCD-sharded atomics ----
    hipMemsetAsync(degS8, 0, (size_t)2 * NSHARD * PN * 4, stream);
    deg_kernel<<<(N_PATHS * N_EDGES + 255) / 256, 256, 0, stream>>>(edges, degS8, degD8);
    norm_reduce_kernel<<<(PN + 255) / 256, 256, 0, stream>>>(degS8, degD8, norm_s, norm_d, degD_tot);
    blocksum_kernel<<<N_PATHS * NBLK_PER_PATH, 256, 0, stream>>>(degD_tot, bsum);
    bscan_kernel<<<N_PATHS, 512, 0, stream>>>(bsum);
    scan_write_kernel<<<N_PATHS * NBLK_PER_PATH, 256, 0, stream>>>(degD_tot, bsum, row_ptr);
    cursor_init_kernel<<<(PN + 255) / 256, 256, 0, stream>>>(row_ptr, degD8, cursor8);
    fill_kernel<<<(N_PATHS * N_EDGES + 255) / 256, 256, 0, stream>>>(edges, norm_s, norm_d, cursor8, cw);

    // ---- one-time casts ----
    cast_kernel<<<(N_NODES * DIM / 4 + 255) / 256, 256, 0, stream>>>(
        (const float4*)h, (ushort4*)hb);
    w1t_kernel<<<(DIM * DIM + 255) / 256, 256, 0, stream>>>(W1, W1t);

    // ---- APPNP propagation: 10 fused layers over all 3 paths ----
    const int pgrid = N_PATHS * N_NODES / 16;   // 18750 blocks, 4 nodes/wave
    prop_kernel<0><<<pgrid, 256, 0, stream>>>(hb, 0, h, buf0, row_ptr, cw);
    for (int i = 1; i <= 8; ++i) {
        const unsigned short* src_b = (i & 1) ? buf0 : buf1;
        unsigned short* dst_b       = (i & 1) ? buf1 : buf0;
        prop_kernel<0><<<pgrid, 256, 0, stream>>>(src_b, PSTRIDE, h, dst_b, row_ptr, cw);
    }
    prop_kernel<1><<<pgrid, 256, 0, stream>>>(buf0, PSTRIDE, h, z, row_ptr, cw);

    // ---- semantic attention (MFMA) ----
    hipMemsetAsync(wsum, 0, 3 * 4, stream);
    attn_kernel<<<512, 256, 0, stream>>>(z, W1t, b1, w2, wsum);
    beta_kernel<<<1, 64, 0, stream>>>(wsum, beta);
    combine_kernel<<<(N_NODES * 32 + 255) / 256, 256, 0, stream>>>(
        (const float4*)z, beta, (float4*)out);
}

// Round 9
// 1109.534 us; speedup vs baseline: 1.7459x; 1.0742x over previous
//
#include <hip/hip_runtime.h>
#include <math.h>

#define N_NODES 100000
#define N_EDGES 500000
#define N_PATHS 3
#define DIM 128
#define K_LAYERS 10
#define NBLK_PER_PATH ((N_NODES + 255) / 256)   // 391
#define PN (N_PATHS * N_NODES)                  // 300000
#define HRANGE 16384                            // LDS histogram bins (64 KB of int)
#define NRANGE ((N_NODES + HRANGE - 1) / HRANGE) // 7
#define BPG 8                                   // blocks per histogram group

typedef __attribute__((ext_vector_type(8))) short bf16x8;
typedef __attribute__((ext_vector_type(4))) float f32x4;

__device__ __forceinline__ float bflo(unsigned u) { return __uint_as_float(u << 16); }
__device__ __forceinline__ float bfhi(unsigned u) { return __uint_as_float(u & 0xffff0000u); }

// ---------------- degree histograms via LDS privatization (NO global atomics) ----
// group g = (p, t, r): path p, array t (0=src,1=dst), node range [r*HRANGE, ...).
// Each of BPG blocks histograms its chunk into LDS, dumps a private partial slice.
__global__ __launch_bounds__(256) void hist_kernel(const int* __restrict__ edges,
                                                   int* __restrict__ partial) {
    __shared__ int hist[HRANGE];
    int g = blockIdx.x / BPG;
    int b = blockIdx.x - g * BPG;
    int r = g % NRANGE;
    int pt = g / NRANGE;           // p*2 + t
    int p = pt >> 1, t = pt & 1;
    for (int i = threadIdx.x; i < HRANGE; i += 256) hist[i] = 0;
    __syncthreads();
    const int* arr = edges + ((size_t)p * 2 + t) * N_EDGES;
    int lo = r * HRANGE;
    const int chunk = N_EDGES / BPG;           // 62500
    int beg = b * chunk;
    for (int i = beg + threadIdx.x; i < beg + chunk; i += 256) {
        int v = arr[i] - lo;
        if ((unsigned)v < HRANGE) atomicAdd(&hist[v], 1);   // LDS atomic, CU-local
    }
    __syncthreads();
    int* outp = partial + ((size_t)g * BPG + b) * HRANGE;
    for (int i = threadIdx.x; i < HRANGE; i += 256) outp[i] = hist[i];
}

// ---------------- reduce partials -> norms + total in-degree ----------------
__global__ __launch_bounds__(256) void deg_reduce_kernel(const int* __restrict__ partial,
                                                         float* __restrict__ norm_s,
                                                         float* __restrict__ norm_d,
                                                         int* __restrict__ degD_tot) {
    int i = blockIdx.x * 256 + threadIdx.x;
    if (i >= PN) return;
    int p = i / N_NODES, n = i - p * N_NODES;
    int r = n / HRANGE, off = n - r * HRANGE;
    const int* ps = partial + (((size_t)(p * 2 + 0) * NRANGE + r) * BPG) * HRANGE + off;
    const int* pd = partial + (((size_t)(p * 2 + 1) * NRANGE + r) * BPG) * HRANGE + off;
    int sS = 0, sD = 0;
#pragma unroll
    for (int b = 0; b < BPG; ++b) {
        sS += ps[(size_t)b * HRANGE];
        sD += pd[(size_t)b * HRANGE];
    }
    norm_s[i] = 1.0f / sqrtf(fmaxf((float)sS, 1.0f));
    norm_d[i] = 1.0f / sqrtf(fmaxf((float)sD, 1.0f));
    degD_tot[i] = sD;
}

// ---------------- hierarchical scan: phase A - per-block sums ----------------
__global__ __launch_bounds__(256) void blocksum_kernel(const int* __restrict__ cnt,
                                                       int* __restrict__ bsum) {
    int b = blockIdx.x;
    int p = b / NBLK_PER_PATH;
    int lb = b - p * NBLK_PER_PATH;
    int idx = lb * 256 + threadIdx.x;
    int v = (idx < N_NODES) ? cnt[p * N_NODES + idx] : 0;
#pragma unroll
    for (int off = 32; off; off >>= 1) v += __shfl_xor(v, off);
    __shared__ int ws[4];
    if ((threadIdx.x & 63) == 0) ws[threadIdx.x >> 6] = v;
    __syncthreads();
    if (threadIdx.x == 0) bsum[b] = ws[0] + ws[1] + ws[2] + ws[3];
}

// ---------------- phase B - scan the 391 block sums per path (3 blocks) --------
__global__ __launch_bounds__(512) void bscan_kernel(int* __restrict__ bsum) {
    __shared__ int s[512];
    int p = blockIdx.x;
    int t = threadIdx.x;
    int v = (t < NBLK_PER_PATH) ? bsum[p * NBLK_PER_PATH + t] : 0;
    s[t] = v;
    __syncthreads();
    for (int off = 1; off < 512; off <<= 1) {
        int x = s[t];
        int a = (t >= off) ? s[t - off] : 0;
        __syncthreads();
        s[t] = x + a;
        __syncthreads();
    }
    if (t < NBLK_PER_PATH) bsum[p * NBLK_PER_PATH + t] = s[t] - v;   // exclusive
}

// ---------------- phase C - block-local rescan + write row_ptr/cursor ----------
__global__ __launch_bounds__(256) void scan_write_kernel(const int* __restrict__ cnt,
                                                         const int* __restrict__ bsum,
                                                         int* __restrict__ row_ptr_all,
                                                         int* __restrict__ cursor_all) {
    __shared__ int s[256];
    int b = blockIdx.x;
    int p = b / NBLK_PER_PATH;
    int lb = b - p * NBLK_PER_PATH;
    int idx = lb * 256 + threadIdx.x;
    int t = threadIdx.x;
    int v = (idx < N_NODES) ? cnt[p * N_NODES + idx] : 0;
    s[t] = v;
    __syncthreads();
    for (int off = 1; off < 256; off <<= 1) {
        int x = s[t];
        int a = (t >= off) ? s[t - off] : 0;
        __syncthreads();
        s[t] = x + a;
        __syncthreads();
    }
    int excl = s[t] - v + bsum[b];
    if (idx < N_NODES) {
        row_ptr_all[p * (N_NODES + 1) + idx] = excl;
        cursor_all[p * N_NODES + idx] = excl;
        if (idx == N_NODES - 1)
            row_ptr_all[p * (N_NODES + 1) + N_NODES] = excl + v;
    }
}

// ---------------- fill CSR: col=src, weight=0.9*norm_s[src]*norm_d[dst] --------
__global__ __launch_bounds__(256) void fill_kernel(const int* __restrict__ edges,
                                                   const float* __restrict__ norm_s,
                                                   const float* __restrict__ norm_d,
                                                   int* __restrict__ cursor,
                                                   int2* __restrict__ cw) {
    int idx = blockIdx.x * 256 + threadIdx.x;
    if (idx < N_PATHS * N_EDGES) {
        int p = idx / N_EDGES;
        int e = idx - p * N_EDGES;
        const int* src = edges + (size_t)p * 2 * N_EDGES;
        const int* dst = src + N_EDGES;
        int s = src[e], d = dst[e];
        int pos = atomicAdd(&cursor[p * N_NODES + d], 1);
        float w = 0.9f * norm_s[p * N_NODES + s] * norm_d[p * N_NODES + d];
        cw[(size_t)p * N_EDGES + pos] = make_int2(s, __float_as_int(w));
    }
}

__device__ __forceinline__ unsigned bf16pack(float a, float b) {
    unsigned ua = __float_as_uint(a), ub = __float_as_uint(b);
    ua = (ua + 0x7fffu + ((ua >> 16) & 1)) >> 16;
    ub = (ub + 0x7fffu + ((ub >> 16) & 1)) >> 16;
    return ua | (ub << 16);
}

// ---------------- f32 -> bf16 cast of h (once) ----------------
__global__ __launch_bounds__(256) void cast_kernel(const float4* __restrict__ in,
                                                   ushort4* __restrict__ outp) {
    int idx = blockIdx.x * 256 + threadIdx.x;
    if (idx < N_NODES * DIM / 4) {
        float4 v = in[idx];
        ushort4 o;
        unsigned u;
        u = __float_as_uint(v.x); o.x = (unsigned short)((u + 0x7fff + ((u >> 16) & 1)) >> 16);
        u = __float_as_uint(v.y); o.y = (unsigned short)((u + 0x7fff + ((u >> 16) & 1)) >> 16);
        u = __float_as_uint(v.z); o.z = (unsigned short)((u + 0x7fff + ((u >> 16) & 1)) >> 16);
        u = __float_as_uint(v.w); o.w = (unsigned short)((u + 0x7fff + ((u >> 16) & 1)) >> 16);
        outp[idx] = o;
    }
}

// ---------------- W1^T bf16 (128x128, once) ----------------
__global__ __launch_bounds__(256) void w1t_kernel(const float* __restrict__ W1,
                                                  unsigned short* __restrict__ W1t) {
    int idx = blockIdx.x * 256 + threadIdx.x;
    if (idx < DIM * DIM) {
        int c = idx >> 7, k = idx & 127;     // W1t[c][k] = bf16(W1[k][c])
        unsigned u = __float_as_uint(W1[k * DIM + c]);
        W1t[idx] = (unsigned short)((u + 0x7fff + ((u >> 16) & 1)) >> 16);
    }
}

// ---------------- one APPNP layer, bf16 state, quarter-wave: 4 nodes per wave ----
// H_BF16=1: anchor read from shared bf16 hb (one uint4 = all 8 elems); layer 9
// uses H_BF16=0 (f32 h anchor) and writes f32 z.
template <int OUT_F32, int H_BF16>
__global__ __launch_bounds__(256) void prop_kernel(const unsigned short* __restrict__ xin,
                                                   size_t in_stride,    // elems per path (0 = shared)
                                                   const void* __restrict__ anchor,
                                                   void* __restrict__ xout,
                                                   const int* __restrict__ row_ptr,
                                                   const int2* __restrict__ cw) {
    int wid  = threadIdx.x >> 6;
    int lane = threadIdx.x & 63;
    int q    = lane >> 4;          // quarter 0..3 = node slot
    int ql   = lane & 15;          // uint4 column within row
    int nodeBase = blockIdx.x * 16 + wid * 4;    // wave-uniform; one path per wave
    int p  = nodeBase / N_NODES;
    int nb = nodeBase - p * N_NODES;
    const int*  rp   = row_ptr + p * (N_NODES + 1);
    const int2* cwp  = cw + (size_t)p * N_EDGES;
    const uint4* xin4 = (const uint4*)(xin + (size_t)p * in_stride);

    int rv = 0;
    if (lane < 5) rv = rp[nb + lane];
    int beg = __shfl(rv, q);
    int end = __shfl(rv, q + 1);
    int deg = end - beg;
    int myNode = nb + q;
    int maxd = deg;
    maxd = max(maxd, __shfl_xor(maxd, 16));
    maxd = max(maxd, __shfl_xor(maxd, 32));

    float a0 = 0.f, a1 = 0.f, a2 = 0.f, a3 = 0.f;
    float a4 = 0.f, a5 = 0.f, a6 = 0.f, a7 = 0.f;

    for (int base = 0; base < maxd; base += 16) {
        int2 e = make_int2(0, 0);
        if (base + ql < deg) e = cwp[beg + base + ql];   // per-quarter coalesced preload
        int lim = maxd - base; if (lim > 16) lim = 16;
#pragma unroll 4
        for (int j = 0; j < lim; ++j) {
            int lsrc = (lane & 48) | j;
            int   c = __shfl(e.x, lsrc);
            float w = __int_as_float(__shfl(e.y, lsrc));
            if (base + j < deg) {      // quarter-uniform exec mask
                uint4 v = xin4[(size_t)c * 16 + ql];
                a0 = fmaf(w, bflo(v.x), a0);
                a1 = fmaf(w, bfhi(v.x), a1);
                a2 = fmaf(w, bflo(v.y), a2);
                a3 = fmaf(w, bfhi(v.y), a3);
                a4 = fmaf(w, bflo(v.z), a4);
                a5 = fmaf(w, bfhi(v.z), a5);
                a6 = fmaf(w, bflo(v.w), a6);
                a7 = fmaf(w, bfhi(v.w), a7);
            }
        }
    }

    if (H_BF16) {
        uint4 hv = ((const uint4*)anchor)[(size_t)myNode * 16 + ql];
        a0 += 0.1f * bflo(hv.x); a1 += 0.1f * bfhi(hv.x);
        a2 += 0.1f * bflo(hv.y); a3 += 0.1f * bfhi(hv.y);
        a4 += 0.1f * bflo(hv.z); a5 += 0.1f * bfhi(hv.z);
        a6 += 0.1f * bflo(hv.w); a7 += 0.1f * bfhi(hv.w);
    } else {
        const float4* h4 = (const float4*)anchor + (size_t)myNode * 32;
        float4 h0v = h4[ql * 2];
        float4 h1v = h4[ql * 2 + 1];
        a0 += 0.1f * h0v.x; a1 += 0.1f * h0v.y; a2 += 0.1f * h0v.z; a3 += 0.1f * h0v.w;
        a4 += 0.1f * h1v.x; a5 += 0.1f * h1v.y; a6 += 0.1f * h1v.z; a7 += 0.1f * h1v.w;
    }

    size_t row = (size_t)p * N_NODES + myNode;
    if (OUT_F32) {
        float4* zo = (float4*)xout + row * 32;
        zo[ql * 2]     = make_float4(a0, a1, a2, a3);
        zo[ql * 2 + 1] = make_float4(a4, a5, a6, a7);
    } else {
        uint4 o;
        o.x = bf16pack(a0, a1);
        o.y = bf16pack(a2, a3);
        o.z = bf16pack(a4, a5);
        o.w = bf16pack(a6, a7);
        ((uint4*)xout)[row * 16 + ql] = o;
    }
}

__device__ __forceinline__ float fast_tanh(float x) {
    float e = __expf(2.0f * x);
    return 1.0f - 2.0f / (e + 1.0f);   // == (e-1)/(e+1) == tanh(x)
}

// ---------------- attention logits via MFMA ----------------
__global__ __launch_bounds__(256) void attn_kernel(const float* __restrict__ z,
                                                   const unsigned short* __restrict__ W1t,
                                                   const float* __restrict__ b1,
                                                   const float* __restrict__ w2,
                                                   float* __restrict__ wsum) {
    const int wid  = threadIdx.x >> 6;
    const int lane = threadIdx.x & 63;
    const int c0   = lane & 15;
    const int kh   = lane >> 4;

    const bf16x8* w1t8 = (const bf16x8*)W1t;
    bf16x8 Bf[8][4];
#pragma unroll
    for (int nt = 0; nt < 8; ++nt)
#pragma unroll
        for (int ks = 0; ks < 4; ++ks)
            Bf[nt][ks] = w1t8[(nt * 16 + c0) * 16 + ks * 4 + kh];

    float b1v[8], w2v[8];
#pragma unroll
    for (int nt = 0; nt < 8; ++nt) {
        b1v[nt] = b1[nt * 16 + c0];
        w2v[nt] = w2[nt * 16 + c0];
    }

    float accP0 = 0.f, accP1 = 0.f, accP2 = 0.f;
    const int NTILES = N_PATHS * N_NODES / 16;   // 18750
    const int TPP    = N_NODES / 16;             // 6250
    const int stride = gridDim.x * 4;
    const float4* zf4 = (const float4*)z;

    for (int t = blockIdx.x * 4 + wid; t < NTILES; t += stride) {
        size_t rbase = ((size_t)t * 16 + c0) * 32 + kh * 2;
        bf16x8 Af[4];
#pragma unroll
        for (int ks = 0; ks < 4; ++ks) {
            float4 x0 = zf4[rbase + ks * 8];
            float4 x1 = zf4[rbase + ks * 8 + 1];
            union { uint4 u; bf16x8 v; } cv;
            cv.u.x = bf16pack(x0.x, x0.y);
            cv.u.y = bf16pack(x0.z, x0.w);
            cv.u.z = bf16pack(x1.x, x1.y);
            cv.u.w = bf16pack(x1.z, x1.w);
            Af[ks] = cv.v;
        }
        f32x4 acc[8];
#pragma unroll
        for (int nt = 0; nt < 8; ++nt) acc[nt] = (f32x4){0.f, 0.f, 0.f, 0.f};
#pragma unroll
        for (int nt = 0; nt < 8; ++nt)
#pragma unroll
            for (int ks = 0; ks < 4; ++ks)
                acc[nt] = __builtin_amdgcn_mfma_f32_16x16x32_bf16(Af[ks], Bf[nt][ks], acc[nt], 0, 0, 0);

        float psum = 0.f;
#pragma unroll
        for (int nt = 0; nt < 8; ++nt) {
            psum += fast_tanh(acc[nt][0] + b1v[nt]) * w2v[nt];
            psum += fast_tanh(acc[nt][1] + b1v[nt]) * w2v[nt];
            psum += fast_tanh(acc[nt][2] + b1v[nt]) * w2v[nt];
            psum += fast_tanh(acc[nt][3] + b1v[nt]) * w2v[nt];
        }
#pragma unroll
        for (int off = 32; off; off >>= 1) psum += __shfl_xor(psum, off);
        if (lane == 0) {
            int p = t / TPP;
            if (p == 0) accP0 += psum;
            else if (p == 1) accP1 += psum;
            else accP2 += psum;
        }
    }
    if (lane == 0) {
        if (accP0 != 0.f) atomicAdd(&wsum[0], accP0);
        if (accP1 != 0.f) atomicAdd(&wsum[1], accP1);
        if (accP2 != 0.f) atomicAdd(&wsum[2], accP2);
    }
}

// ---------------- beta = softmax(wsum / N) over 3 paths ----------------
__global__ void beta_kernel(const float* __restrict__ wsum, float* __restrict__ beta) {
    if (threadIdx.x == 0 && blockIdx.x == 0) {
        float w0 = wsum[0] * (1.0f / N_NODES);
        float w1 = wsum[1] * (1.0f / N_NODES);
        float w2v = wsum[2] * (1.0f / N_NODES);
        float m = fmaxf(w0, fmaxf(w1, w2v));
        float e0 = expf(w0 - m), e1 = expf(w1 - m), e2 = expf(w2v - m);
        float inv = 1.0f / (e0 + e1 + e2);
        beta[0] = e0 * inv;
        beta[1] = e1 * inv;
        beta[2] = e2 * inv;
    }
}

// ---------------- out[n,:] = sum_p beta[p] * z[p,n,:] ----------------
__global__ __launch_bounds__(256) void combine_kernel(const float4* __restrict__ z4,
                                                      const float* __restrict__ beta,
                                                      float4* __restrict__ out4) {
    size_t idx = (size_t)blockIdx.x * 256 + threadIdx.x;
    const size_t M = (size_t)N_NODES * 32;
    if (idx < M) {
        float b0 = beta[0], b1 = beta[1], b2 = beta[2];
        float4 a = z4[idx];
        float4 b = z4[M + idx];
        float4 c = z4[2 * M + idx];
        float4 o;
        o.x = b0 * a.x + b1 * b.x + b2 * c.x;
        o.y = b0 * a.y + b1 * b.y + b2 * c.y;
        o.z = b0 * a.z + b1 * b.z + b2 * c.z;
        o.w = b0 * a.w + b1 * b.w + b2 * c.w;
        out4[idx] = o;
    }
}

extern "C" void kernel_launch(void* const* d_in, const int* in_sizes, int n_in,
                              void* d_out, int out_size, void* d_ws, size_t ws_size,
                              hipStream_t stream) {
    const float* h     = (const float*)d_in[0];
    const int*   edges = (const int*)d_in[1];   // (3, 2, 500000) int32
    const float* W1    = (const float*)d_in[2];
    const float* b1    = (const float*)d_in[3];
    const float* w2    = (const float*)d_in[4];
    float* out = (float*)d_out;

    // ---- workspace carve ----
    char* ws = (char*)d_ws;
    float* z = (float*)ws;               ws += (size_t)N_PATHS * N_NODES * DIM * 4;  // 153.6 MB
    unsigned short* buf0 = (unsigned short*)ws; ws += (size_t)N_PATHS * N_NODES * DIM * 2;  // 76.8 MB
    int2* cw = (int2*)ws;                ws += (size_t)N_PATHS * N_EDGES * 8;        // 12 MB
    int* row_ptr = (int*)ws;             ws += (size_t)N_PATHS * (N_NODES + 1) * 4 + 12;
    float* norm_s = (float*)ws;          ws += (size_t)PN * 4;
    float* norm_d = (float*)ws;          ws += (size_t)PN * 4;
    int* bsum = (int*)ws;                ws += (size_t)N_PATHS * NBLK_PER_PATH * 4;
    float* wsum = (float*)ws;            ws += 4 * 4;
    float* beta = (float*)ws;            ws += 4 * 4;
    unsigned short* W1t = (unsigned short*)ws; ws += (size_t)DIM * DIM * 2;          // 32 KB
    // CSR-build temporaries inside buf0 (dead until prop layer 0 writes it):
    int* partial  = (int*)buf0;                               // 22.0 MB
    int* degD_tot = partial + (size_t)3 * 2 * NRANGE * BPG * HRANGE;  // 1.2 MB
    int* cursor   = degD_tot + PN;                            // 1.2 MB  (~24.4 MB total)
    // aliases inside z (dead before layer 9 writes z):
    unsigned short* buf1 = (unsigned short*)z;                                   // 76.8 MB
    unsigned short* hb   = (unsigned short*)z + (size_t)N_PATHS * N_NODES * DIM; // 25.6 MB

    const size_t PSTRIDE = (size_t)N_NODES * DIM;   // per-path elems

    // ---- CSR build: LDS histograms (no global atomics in deg) ----
    hist_kernel<<<3 * 2 * NRANGE * BPG, 256, 0, stream>>>(edges, partial);
    deg_reduce_kernel<<<(PN + 255) / 256, 256, 0, stream>>>(partial, norm_s, norm_d, degD_tot);
    blocksum_kernel<<<N_PATHS * NBLK_PER_PATH, 256, 0, stream>>>(degD_tot, bsum);
    bscan_kernel<<<N_PATHS, 512, 0, stream>>>(bsum);
    scan_write_kernel<<<N_PATHS * NBLK_PER_PATH, 256, 0, stream>>>(degD_tot, bsum, row_ptr, cursor);
    fill_kernel<<<(N_PATHS * N_EDGES + 255) / 256, 256, 0, stream>>>(edges, norm_s, norm_d, cursor, cw);

    // ---- one-time casts ----
    cast_kernel<<<(N_NODES * DIM / 4 + 255) / 256, 256, 0, stream>>>(
        (const float4*)h, (ushort4*)hb);
    w1t_kernel<<<(DIM * DIM + 255) / 256, 256, 0, stream>>>(W1, W1t);

    // ---- APPNP propagation: 10 fused layers over all 3 paths ----
    const int pgrid = N_PATHS * N_NODES / 16;   // 18750 blocks, 4 nodes/wave
    // layers 0..8: bf16 anchor hb (also layer-0 input, stride 0)
    prop_kernel<0, 1><<<pgrid, 256, 0, stream>>>(hb, 0, hb, buf0, row_ptr, cw);
    for (int i = 1; i <= 8; ++i) {
        const unsigned short* src_b = (i & 1) ? buf0 : buf1;
        unsigned short* dst_b       = (i & 1) ? buf1 : buf0;
        prop_kernel<0, 1><<<pgrid, 256, 0, stream>>>(src_b, PSTRIDE, hb, dst_b, row_ptr, cw);
    }
    // layer 9: f32 h anchor, writes f32 z (hb/buf1 dead; no race with z writes)
    prop_kernel<1, 0><<<pgrid, 256, 0, stream>>>(buf0, PSTRIDE, h, z, row_ptr, cw);

    // ---- semantic attention (MFMA) ----
    hipMemsetAsync(wsum, 0, 3 * 4, stream);
    attn_kernel<<<512, 256, 0, stream>>>(z, W1t, b1, w2, wsum);
    beta_kernel<<<1, 64, 0, stream>>>(wsum, beta);
    combine_kernel<<<(N_NODES * 32 + 255) / 256, 256, 0, stream>>>(
        (const float4*)z, beta, (float4*)out);
}